// Round 21
// baseline (93.874 us; speedup 1.0000x reference)
//
#include <hip/hip_runtime.h>
#include <hip/hip_cooperative_groups.h>

namespace cg = cooperative_groups;

// Problem constants (B=16, C=64, H=64, W=64, K=1024, D=64)
#define HWSZ   4096
#define CCH    64
#define KCB    1024
#define NROW   65536
#define NDTOT  4194304
#define MBLK   256             // 1 block per CU (co-resident for grid.sync)
#define BROWS  256             // rows per block (4 waves x 64 rows)

typedef __attribute__((ext_vector_type(8))) short short8;
typedef __attribute__((ext_vector_type(4))) float f32x4;

typedef const __attribute__((address_space(1))) unsigned gas_u32;
typedef __attribute__((address_space(3))) unsigned las_u32;

__device__ __forceinline__ unsigned f2bf_rn(float x) {
    union { float f; unsigned u; } v; v.f = x;
    return (v.u + 0x7fffu + ((v.u >> 16) & 1u)) >> 16;
}

// ---------- single cooperative kernel: convert -> sync -> scan -> sync -> reduce ----------
// r20 ledger: scan 7.3us + A/E 2.5us; remaining ~20.7us was 3-launch serialization
// (prep fully drains before main starts; fin tail; 2 graph gaps). One cooperative
// kernel removes all of it. grid.sync fences land BEFORE staging / AFTER scan, so
// the r13 L2-poisoning failure mode (per-block fences during the scan) is avoided.
__global__ __launch_bounds__(256, 2) void vq_all(const float* __restrict__ z,
                                                 const float* __restrict__ E,
                                                 unsigned* __restrict__ Ebf,
                                                 float* __restrict__ he2b,
                                                 float* __restrict__ out,
                                                 float* __restrict__ partial) {
    __shared__ short lbs[65536];       // 128 KB: full swizzled codebook image
    __shared__ float he2l[1024];       // 4 KB biases
    __shared__ float wsum[4];

    const int t   = threadIdx.x;       // 0..255
    const int blk = blockIdx.x;        // 0..255
    const int n0  = blk * BROWS;
    const int bb  = n0 >> 12;
    const int wid = t >> 6, lane = t & 63, col = lane & 15, g = lane >> 4;
    const int hwb = (n0 & 4095) + wid * 64;          // wave's 64-row hw base
    const float* zw = z + (size_t)bb * CCH * HWSZ + hwb;

    // ---- phase 0: distributed E -> swizzled bf16 ws + he2 (1 dword/thread) ----
    {
        const int gid = blk * 256 + t;               // 0..65535
        if (gid < 32768) {                           // 1024 codes x 32 dwords
            const int code = gid >> 5, dw = gid & 5 * 6 + 1;  // placeholder avoided
        }
    }
    {
        const int gid = blk * 256 + t;
        if (gid < 32768) {
            const int code = gid >> 5, dw = gid & 31;
            float2 v = *(const float2*)(E + (size_t)code * 64 + dw * 2);
            float s = v.x * v.x + v.y * v.y;
            unsigned w = f2bf_rn(v.x) | (f2bf_rn(v.y) << 16);
            Ebf[(unsigned)(code * 32 + dw) ^ (((unsigned)code & 7u) << 2)] = w;
            #pragma unroll
            for (int off = 1; off <= 16; off <<= 1) s += __shfl_xor(s, off, 64);
            if (dw == 0) he2b[code] = 1.0f + 0.5f * s;   // lane-group leader
        }
    }
    cg::this_grid().sync();            // ws visible device-wide; fence BEFORE staging

    // ---- stage full codebook: 8192 x 16B slots, 32/thread (DMA, zero VGPRs) ----
    #pragma unroll
    for (int q = 0; q < 32; ++q) {
        int slot = q * 256 + t;        // dest = wave-uniform base + lane*16  ✓
        __builtin_amdgcn_global_load_lds((gas_u32*)((const char*)Ebf + (size_t)slot * 16),
                                         (las_u32*)((char*)lbs + slot * 16), 16, 0, 0);
    }
    // ---- stage he2: 256 x 16B slots, 1/thread ----
    __builtin_amdgcn_global_load_lds((gas_u32*)((const char*)he2b + (size_t)t * 16),
                                     (las_u32*)((char*)he2l + t * 16), 16, 0, 0);

    // ---- A-frags rt=4 + z^2 from global (overlaps DMA); per-rt fences cap
    // the hoisted-load VGPR peak (r10/r12 spill lesson) ----
    float z2 = 0.f;
    short8 af[4][2];
    #pragma unroll
    for (int rt = 0; rt < 4; ++rt) {
        #pragma unroll
        for (int ch = 0; ch < 2; ++ch) {
            short8 a;
            #pragma unroll
            for (int j = 0; j < 8; ++j) {
                int c = ch * 32 + g * 8 + j;
                float v = zw[(size_t)c * HWSZ + rt * 16 + col];
                z2 = fmaf(v, v, z2);
                union { float f; unsigned u; } uu; uu.f = v;
                a[j] = (short)((uu.u >> 16) ^ 0x8000u);   // -z, bf16 truncation
            }
            af[rt][ch] = a;
        }
        asm volatile("" ::: "memory");
    }

    __syncthreads();   // vmcnt(0) drain before s_barrier: DMAs landed

    float pk[4][4];
    #pragma unroll
    for (int rt = 0; rt < 4; ++rt)
        #pragma unroll
        for (int r = 0; r < 4; ++r) pk[rt][r] = 3.0e38f;

    // per-lane swizzled LDS read offsets (shorts); code&7 == col&7 within a tile
    const int swz = (col & 7) << 3;
    const int ro0 = col * 64 + ((g * 8) ^ swz);
    const int ro1 = col * 64 + ((32 + g * 8) ^ swz);

    // ---- barrier-free scan: 32 code-tile pairs; 4 ds_read_b128 -> 16 MFMA each ----
    #pragma unroll 2
    for (int cp = 0; cp < 32; ++cp) {
        const int ct0 = cp * 2, ct1 = ct0 + 1;
        const short* Lb0 = lbs + ct0 * 1024;
        const short* Lb1 = lbs + ct1 * 1024;
        short8 b00 = *(const short8*)(Lb0 + ro0);
        short8 b01 = *(const short8*)(Lb0 + ro1);
        short8 b10 = *(const short8*)(Lb1 + ro0);
        short8 b11 = *(const short8*)(Lb1 + ro1);
        const float h0 = he2l[ct0 * 16 + col];       // broadcast reads
        const float h1 = he2l[ct1 * 16 + col];
        const unsigned code0 = (unsigned)(ct0 * 16 + col);
        const unsigned code1 = code0 + 16;
        f32x4 hv0 = {h0, h0, h0, h0};
        f32x4 hv1 = {h1, h1, h1, h1};
        #pragma unroll
        for (int rt = 0; rt < 4; ++rt) {
            f32x4 a0 = __builtin_amdgcn_mfma_f32_16x16x32_bf16(af[rt][0], b00, hv0, 0, 0, 0);
            a0 = __builtin_amdgcn_mfma_f32_16x16x32_bf16(af[rt][1], b01, a0, 0, 0, 0);
            f32x4 a1 = __builtin_amdgcn_mfma_f32_16x16x32_bf16(af[rt][0], b10, hv1, 0, 0, 0);
            a1 = __builtin_amdgcn_mfma_f32_16x16x32_bf16(af[rt][1], b11, a1, 0, 0, 0);
            #pragma unroll
            for (int r = 0; r < 4; ++r) {
                union { float f; unsigned u; } m0, m1;
                m0.f = a0[r]; m0.u = (m0.u & 0xFFFFFC00u) | code0;   // v_and_or_b32
                m1.f = a1[r]; m1.u = (m1.u & 0xFFFFFC00u) | code1;
                pk[rt][r] = fminf(fminf(pk[rt][r], m0.f), m1.f);     // v_min3_f32
            }
        }
    }

    // ---- butterfly min over 16 code-columns ----
    #pragma unroll
    for (int rt = 0; rt < 4; ++rt) {
        #pragma unroll
        for (int r = 0; r < 4; ++r) {
            float d = pk[rt][r];
            #pragma unroll
            for (int mask = 1; mask < 16; mask <<= 1)
                d = fminf(d, __shfl_xor(d, mask, 64));
            pk[rt][r] = d;
        }
    }

    // ---- epilogue: output = E rows (== z + (q - z) to 1 ulp), loss from scores ----
    float lsum = z2;
    const int rowbase = n0 + wid * 64;
    #pragma unroll
    for (int rt = 0; rt < 4; ++rt) {
        #pragma unroll
        for (int r = 0; r < 4; ++r) {
            union { float f; unsigned u; } b; b.f = pk[rt][r];
            unsigned kk = b.u & 1023u;
            if (col == 0) {                              // count each row's score once
                union { unsigned u; float f; } sc; sc.u = b.u & 0xFFFFFC00u;
                lsum += 2.0f * (sc.f - 1.0f);            // ||e||^2 - 2 z.e
            }
            int row = rt * 16 + g * 4 + r;
            float4 qv = *(const float4*)(E + (size_t)kk * 64 + col * 4);
            *(float4*)(out + ((size_t)(rowbase + row)) * 64 + col * 4) = qv;
        }
    }

    #pragma unroll
    for (int off = 32; off >= 1; off >>= 1) lsum += __shfl_down(lsum, off, 64);
    if (lane == 0) wsum[wid] = lsum;
    __syncthreads();
    if (t == 0) partial[blk] = (wsum[0] + wsum[1]) + (wsum[2] + wsum[3]);

    // ---- final: grid-wide sync, block 0 reduces losses (replaces fin launch) ----
    cg::this_grid().sync();
    if (blk == 0) {
        float* ps = (float*)lbs;                 // reuse LDS as 256-float scratch
        ps[t] = partial[t];
        __syncthreads();
        for (int st = 128; st >= 1; st >>= 1) {
            if (t < st) ps[t] += ps[t + st];
            __syncthreads();
        }
        if (t == 0) {
            float mse = ps[0] / (float)NDTOT;
            out[NDTOT]     = 0.25f * mse;        // commitment_loss
            out[NDTOT + 1] = mse;                // codebook_loss
        }
    }
}

// ---------- fallback fp32 path (round-1, correctness-proven) ----------
__global__ __launch_bounds__(64) void vq_init(float* out) {
    if (threadIdx.x == 0) { out[NDTOT] = 0.0f; out[NDTOT + 1] = 0.0f; }
}

__global__ __launch_bounds__(256, 4) void vq_main_fp32(const float* __restrict__ z,
                                                       const float* __restrict__ E,
                                                       float* __restrict__ out,
                                                       float* __restrict__ partial) {
    __shared__ float zs[64][65];
    __shared__ float e2s[KCB];
    __shared__ float wmin[4][64];
    __shared__ int   widx[4][64];
    __shared__ int   rowidx[64];
    __shared__ float wsum[4];

    const int t   = threadIdx.x;
    const int blk = blockIdx.x;
    const int n0  = blk << 6;
    const int bb  = n0 >> 12;
    const int hw0 = n0 & 4095;
    const float* zb = z + (size_t)bb * CCH * HWSZ + hw0;

    #pragma unroll
    for (int j = 0; j < 16; ++j) {
        int f = t + 256 * j;
        int c = f >> 6, i = f & 63;
        zs[c][i] = zb[(size_t)c * HWSZ + i];
    }
    for (int qq = t; qq < KCB; qq += 256) {
        const float4* ep = (const float4*)(E + (size_t)qq * 64);
        float s0 = 0.f;
        #pragma unroll
        for (int c4 = 0; c4 < 16; ++c4) {
            float4 a = ep[c4];
            s0 += a.x * a.x + a.y * a.y + a.z * a.z + a.w * a.w;
        }
        e2s[qq] = s0;
    }
    __syncthreads();

    const int i   = t & 63;
    const int wid = t >> 6;
    float zr[64];
    #pragma unroll
    for (int c = 0; c < 64; ++c) zr[c] = zs[c][i];

    float best = 3.4e38f;
    int   bi = 0;
    const int k0 = wid << 8;
    const float* Ew = E + (size_t)k0 * 64;
    for (int kk = 0; kk < 256; ++kk) {
        const float4* ek = (const float4*)(Ew + (size_t)kk * 64);
        float d0 = 0.f, d1 = 0.f, d2 = 0.f, d3 = 0.f;
        #pragma unroll
        for (int c4 = 0; c4 < 16; ++c4) {
            float4 a = ek[c4];
            d0 = fmaf(a.x, zr[4 * c4 + 0], d0);
            d1 = fmaf(a.y, zr[4 * c4 + 1], d1);
            d2 = fmaf(a.z, zr[4 * c4 + 2], d2);
            d3 = fmaf(a.w, zr[4 * c4 + 3], d3);
        }
        float dot  = (d0 + d1) + (d2 + d3);
        float dist = fmaf(-2.0f, dot, e2s[k0 + kk]);
        if (dist < best) { best = dist; bi = k0 + kk; }
    }
    wmin[wid][i] = best; widx[wid][i] = bi;
    __syncthreads();
    if (t < 64) {
        float m = wmin[0][t]; int ix = widx[0][t];
        #pragma unroll
        for (int w = 1; w < 4; ++w) {
            float v = wmin[w][t]; int x = widx[w][t];
            if (v < m) { m = v; ix = x; }
        }
        rowidx[t] = ix;
    }
    __syncthreads();

    float lsum = 0.f;
    const size_t base = (size_t)blk * 4096;
    float* oflat = out + base;
    #pragma unroll
    for (int j = 0; j < 16; ++j) {
        int f  = t + 256 * j;
        int nl = f >> 6, d = f & 63;
        int k  = rowidx[nl];
        float qv = E[(size_t)k * 64 + d];
        float zf = zs[d][nl];
        float df = qv - zf;
        lsum += df * df;
        oflat[f] = qv;
    }
    #pragma unroll
    for (int off = 32; off >= 1; off >>= 1) lsum += __shfl_down(lsum, off, 64);
    if (i == 0) wsum[wid] = lsum;
    __syncthreads();
    if (t == 0) {
        float s = (wsum[0] + wsum[1]) + (wsum[2] + wsum[3]);
        if (partial) partial[blk] = s;
        else         atomicAdd(&out[NDTOT + 1], s);
    }
}

__global__ __launch_bounds__(256) void vq_fin(const float* __restrict__ partial,
                                              float* __restrict__ out, int npart) {
    if (npart > 0) {
        __shared__ float ps[256];
        float s = 0.f;
        for (int qq = threadIdx.x; qq < npart; qq += 256) s += partial[qq];
        ps[threadIdx.x] = s;
        __syncthreads();
        for (int st = 128; st >= 1; st >>= 1) {
            if (threadIdx.x < st) ps[threadIdx.x] += ps[threadIdx.x + st];
            __syncthreads();
        }
        if (threadIdx.x == 0) {
            float mse = ps[0] / (float)NDTOT;
            out[NDTOT]     = 0.25f * mse;   // commitment_loss
            out[NDTOT + 1] = mse;           // codebook_loss
        }
    } else {
        if (threadIdx.x == 0) {
            float mse = out[NDTOT + 1] / (float)NDTOT;
            out[NDTOT]     = 0.25f * mse;
            out[NDTOT + 1] = mse;
        }
    }
}

extern "C" void kernel_launch(void* const* d_in, const int* in_sizes, int n_in,
                              void* d_out, int out_size, void* d_ws, size_t ws_size,
                              hipStream_t stream) {
    const float* z = (const float*)d_in[0];
    const float* E = (const float*)d_in[1];
    float* out = (float*)d_out;

    const size_t EBF_BYTES = (size_t)KCB * 64 * 2;                 // 131072
    const size_t need = EBF_BYTES + 4096 + MBLK * sizeof(float);   // Ebf + he2b + partial

    if (ws_size >= need) {
        unsigned* Ebf  = (unsigned*)d_ws;
        float* he2b    = (float*)((char*)d_ws + EBF_BYTES);
        float* partial = (float*)((char*)d_ws + EBF_BYTES + 4096);
        void* args[] = {(void*)&z, (void*)&E, (void*)&Ebf, (void*)&he2b,
                        (void*)&out, (void*)&partial};
        hipLaunchCooperativeKernel((const void*)vq_all, dim3(MBLK), dim3(256),
                                   args, 0, stream);
    } else {
        hipLaunchKernelGGL(vq_init, dim3(1), dim3(64), 0, stream, out);
        hipLaunchKernelGGL(vq_main_fp32, dim3(1024), dim3(256), 0, stream, z, E, out, nullptr);
        hipLaunchKernelGGL(vq_fin, dim3(1), dim3(256), 0, stream, nullptr, out, 0);
    }
}

// Round 22
// 34.036 us; speedup vs baseline: 2.7581x; 2.7581x over previous
//
#include <hip/hip_runtime.h>

// Problem constants (B=16, C=64, H=64, W=64, K=1024, D=64)
#define HWSZ   4096
#define CCH    64
#define KCB    1024
#define NROW   65536
#define NDTOT  4194304
#define MBLK   256             // main-path blocks (1 per CU)
#define BROWS  256             // rows per block (4 waves x 64 rows)

typedef __attribute__((ext_vector_type(8))) short short8;
typedef __attribute__((ext_vector_type(4))) float f32x4;

typedef const __attribute__((address_space(1))) unsigned gas_u32;
typedef __attribute__((address_space(3))) unsigned las_u32;

__device__ __forceinline__ unsigned short f2bf_rn(float x) {
    union { float f; unsigned u; } v; v.f = x;
    unsigned r = (v.u + 0x7fffu + ((v.u >> 16) & 1u)) >> 16;
    return (unsigned short)r;
}

// ---------- prep: 16 blocks, 4 threads/code: E -> swizzled bf16 + he2b;
// block 0 also zeroes the two loss slots (runs before main in stream order,
// every replay -> main's atomicAdd tail accumulates onto clean zeros) ----------
__global__ __launch_bounds__(256) void vq_prep(const float* __restrict__ E,
                                               unsigned* __restrict__ Ebf,
                                               float* __restrict__ he2b,
                                               float* __restrict__ out) {
    const int t = threadIdx.x;
    if (blockIdx.x == 0 && t == 0) { out[NDTOT] = 0.0f; out[NDTOT + 1] = 0.0f; }
    const int gid  = blockIdx.x * 256 + t;
    const int code = gid >> 2;           // 0..1023
    const int part = gid & 3;
    const float4* ep = (const float4*)(E + (size_t)code * 64 + part * 16);
    const unsigned sw = ((unsigned)code & 7u) << 2;   // T2 swizzle on dword index
    float s = 0.f;
    #pragma unroll
    for (int q = 0; q < 4; ++q) {
        float4 a = ep[q];
        s += a.x * a.x + a.y * a.y + a.z * a.z + a.w * a.w;
        unsigned lo = (unsigned)f2bf_rn(a.x) | ((unsigned)f2bf_rn(a.y) << 16);
        unsigned hi = (unsigned)f2bf_rn(a.z) | ((unsigned)f2bf_rn(a.w) << 16);
        unsigned base = (unsigned)code * 32 + part * 8 + q * 2;
        Ebf[base ^ sw]       = lo;       // (base+1)^sw == (base^sw)+1 (sw bits >= 2)
        Ebf[(base + 1) ^ sw] = hi;
    }
    s += __shfl_xor(s, 1, 64);
    s += __shfl_xor(s, 2, 64);
    if (part == 0) he2b[code] = 1.0f + 0.5f * s;
}

// ---------- main: r19 kernel; loss tail = 2 plain atomicAdds per block ----------
// (replaces the vq_fin launch; NO fences/tickets/grid-sync -- r13/r21 lesson:
// in-kernel device-wide sync costs 25-30us on this chip. Plain device-scope
// atomics at block end are coherent (G12) and don't flush caches.)
__global__ __launch_bounds__(256, 2) void vq_mfma(const float* __restrict__ z,
                                                  const float* __restrict__ E,
                                                  const short* __restrict__ Ebf,
                                                  const float* __restrict__ he2g,
                                                  float* __restrict__ out) {
    __shared__ short lbs[65536];       // 128 KB: full swizzled codebook image
    __shared__ float he2l[1024];       // 4 KB biases
    __shared__ float wsum[4];

    const int t   = threadIdx.x;       // 0..255
    const int blk = blockIdx.x;        // 0..255
    const int n0  = blk * BROWS;
    const int bb  = n0 >> 12;
    const int wid = t >> 6, lane = t & 63, col = lane & 15, g = lane >> 4;
    const int hwb = (n0 & 4095) + wid * 64;          // wave's 64-row hw base
    const float* zw = z + (size_t)bb * CCH * HWSZ + hwb;

    // ---- stage full codebook: 8192 x 16B slots, 32 per thread (DMA, zero VGPRs) ----
    #pragma unroll
    for (int q = 0; q < 32; ++q) {
        int slot = q * 256 + t;        // dest = wave-uniform base + lane*16  ✓
        __builtin_amdgcn_global_load_lds((gas_u32*)((const char*)Ebf + (size_t)slot * 16),
                                         (las_u32*)((char*)lbs + slot * 16), 16, 0, 0);
    }
    // ---- stage he2: 256 x 16B slots, 1 per thread ----
    __builtin_amdgcn_global_load_lds((gas_u32*)((const char*)he2g + (size_t)t * 16),
                                     (las_u32*)((char*)he2l + t * 16), 16, 0, 0);

    // ---- A-frags rt=4 (64 rows/wave) + z^2, from global (overlaps DMA);
    // per-rt fences cap the hoisted-load VGPR peak (r10/r12 spill lesson) ----
    float z2 = 0.f;
    short8 af[4][2];
    #pragma unroll
    for (int rt = 0; rt < 4; ++rt) {
        #pragma unroll
        for (int ch = 0; ch < 2; ++ch) {
            short8 a;
            #pragma unroll
            for (int j = 0; j < 8; ++j) {
                int c = ch * 32 + g * 8 + j;
                float v = zw[(size_t)c * HWSZ + rt * 16 + col];
                z2 = fmaf(v, v, z2);
                union { float f; unsigned u; } uu; uu.f = v;
                a[j] = (short)((uu.u >> 16) ^ 0x8000u);   // -z, bf16 truncation
            }
            af[rt][ch] = a;
        }
        asm volatile("" ::: "memory");
    }

    __syncthreads();   // compiler emits vmcnt(0) drain before s_barrier: DMAs landed

    float pk[4][4];
    #pragma unroll
    for (int rt = 0; rt < 4; ++rt)
        #pragma unroll
        for (int r = 0; r < 4; ++r) pk[rt][r] = 3.0e38f;

    // per-lane swizzled LDS read offsets (shorts); code&7 == col&7 within a tile
    const int swz = (col & 7) << 3;
    const int ro0 = col * 64 + ((g * 8) ^ swz);
    const int ro1 = col * 64 + ((32 + g * 8) ^ swz);

    // ---- barrier-free scan: 32 code-tile pairs; 4 ds_read_b128 -> 16 MFMA each ----
    #pragma unroll 2
    for (int cp = 0; cp < 32; ++cp) {
        const int ct0 = cp * 2, ct1 = ct0 + 1;
        const short* Lb0 = lbs + ct0 * 1024;
        const short* Lb1 = lbs + ct1 * 1024;
        short8 b00 = *(const short8*)(Lb0 + ro0);
        short8 b01 = *(const short8*)(Lb0 + ro1);
        short8 b10 = *(const short8*)(Lb1 + ro0);
        short8 b11 = *(const short8*)(Lb1 + ro1);
        const float h0 = he2l[ct0 * 16 + col];       // broadcast reads
        const float h1 = he2l[ct1 * 16 + col];
        const unsigned code0 = (unsigned)(ct0 * 16 + col);
        const unsigned code1 = code0 + 16;
        f32x4 hv0 = {h0, h0, h0, h0};
        f32x4 hv1 = {h1, h1, h1, h1};
        #pragma unroll
        for (int rt = 0; rt < 4; ++rt) {
            f32x4 a0 = __builtin_amdgcn_mfma_f32_16x16x32_bf16(af[rt][0], b00, hv0, 0, 0, 0);
            a0 = __builtin_amdgcn_mfma_f32_16x16x32_bf16(af[rt][1], b01, a0, 0, 0, 0);
            f32x4 a1 = __builtin_amdgcn_mfma_f32_16x16x32_bf16(af[rt][0], b10, hv1, 0, 0, 0);
            a1 = __builtin_amdgcn_mfma_f32_16x16x32_bf16(af[rt][1], b11, a1, 0, 0, 0);
            #pragma unroll
            for (int r = 0; r < 4; ++r) {
                union { float f; unsigned u; } m0, m1;
                m0.f = a0[r]; m0.u = (m0.u & 0xFFFFFC00u) | code0;   // v_and_or_b32
                m1.f = a1[r]; m1.u = (m1.u & 0xFFFFFC00u) | code1;
                pk[rt][r] = fminf(fminf(pk[rt][r], m0.f), m1.f);     // v_min3_f32
            }
        }
    }

    // ---- butterfly min over 16 code-columns ----
    #pragma unroll
    for (int rt = 0; rt < 4; ++rt) {
        #pragma unroll
        for (int r = 0; r < 4; ++r) {
            float d = pk[rt][r];
            #pragma unroll
            for (int mask = 1; mask < 16; mask <<= 1)
                d = fminf(d, __shfl_xor(d, mask, 64));
            pk[rt][r] = d;
        }
    }

    // ---- epilogue: output = E rows (== z + (q - z) to 1 ulp), loss from scores ----
    float lsum = z2;
    const int rowbase = n0 + wid * 64;
    #pragma unroll
    for (int rt = 0; rt < 4; ++rt) {
        #pragma unroll
        for (int r = 0; r < 4; ++r) {
            union { float f; unsigned u; } b; b.f = pk[rt][r];
            unsigned kk = b.u & 1023u;
            if (col == 0) {                              // count each row's score once
                union { unsigned u; float f; } sc; sc.u = b.u & 0xFFFFFC00u;
                lsum += 2.0f * (sc.f - 1.0f);            // ||e||^2 - 2 z.e
            }
            int row = rt * 16 + g * 4 + r;
            float4 qv = *(const float4*)(E + (size_t)kk * 64 + col * 4);
            *(float4*)(out + ((size_t)(rowbase + row)) * 64 + col * 4) = qv;
        }
    }

    #pragma unroll
    for (int off = 32; off >= 1; off >>= 1) lsum += __shfl_down(lsum, off, 64);
    if (lane == 0) wsum[wid] = lsum;
    __syncthreads();
    if (t == 0) {
        float s = (wsum[0] + wsum[1]) + (wsum[2] + wsum[3]);
        float m = s * (1.0f / (float)NDTOT);
        atomicAdd(&out[NDTOT],     0.25f * m);   // commitment_loss
        atomicAdd(&out[NDTOT + 1], m);           // codebook_loss
    }
}

// ---------- fallback fp32 path (round-1, correctness-proven) ----------
__global__ __launch_bounds__(64) void vq_init(float* out) {
    if (threadIdx.x == 0) { out[NDTOT] = 0.0f; out[NDTOT + 1] = 0.0f; }
}

__global__ __launch_bounds__(256, 4) void vq_main_fp32(const float* __restrict__ z,
                                                       const float* __restrict__ E,
                                                       float* __restrict__ out,
                                                       float* __restrict__ partial) {
    __shared__ float zs[64][65];
    __shared__ float e2s[KCB];
    __shared__ float wmin[4][64];
    __shared__ int   widx[4][64];
    __shared__ int   rowidx[64];
    __shared__ float wsum[4];

    const int t   = threadIdx.x;
    const int blk = blockIdx.x;
    const int n0  = blk << 6;
    const int bb  = n0 >> 12;
    const int hw0 = n0 & 4095;
    const float* zb = z + (size_t)bb * CCH * HWSZ + hw0;

    #pragma unroll
    for (int j = 0; j < 16; ++j) {
        int f = t + 256 * j;
        int c = f >> 6, i = f & 63;
        zs[c][i] = zb[(size_t)c * HWSZ + i];
    }
    for (int qq = t; qq < KCB; qq += 256) {
        const float4* ep = (const float4*)(E + (size_t)qq * 64);
        float s0 = 0.f;
        #pragma unroll
        for (int c4 = 0; c4 < 16; ++c4) {
            float4 a = ep[c4];
            s0 += a.x * a.x + a.y * a.y + a.z * a.z + a.w * a.w;
        }
        e2s[qq] = s0;
    }
    __syncthreads();

    const int i   = t & 63;
    const int wid = t >> 6;
    float zr[64];
    #pragma unroll
    for (int c = 0; c < 64; ++c) zr[c] = zs[c][i];

    float best = 3.4e38f;
    int   bi = 0;
    const int k0 = wid << 8;
    const float* Ew = E + (size_t)k0 * 64;
    for (int kk = 0; kk < 256; ++kk) {
        const float4* ek = (const float4*)(Ew + (size_t)kk * 64);
        float d0 = 0.f, d1 = 0.f, d2 = 0.f, d3 = 0.f;
        #pragma unroll
        for (int c4 = 0; c4 < 16; ++c4) {
            float4 a = ek[c4];
            d0 = fmaf(a.x, zr[4 * c4 + 0], d0);
            d1 = fmaf(a.y, zr[4 * c4 + 1], d1);
            d2 = fmaf(a.z, zr[4 * c4 + 2], d2);
            d3 = fmaf(a.w, zr[4 * c4 + 3], d3);
        }
        float dot  = (d0 + d1) + (d2 + d3);
        float dist = fmaf(-2.0f, dot, e2s[k0 + kk]);
        if (dist < best) { best = dist; bi = k0 + kk; }
    }
    wmin[wid][i] = best; widx[wid][i] = bi;
    __syncthreads();
    if (t < 64) {
        float m = wmin[0][t]; int ix = widx[0][t];
        #pragma unroll
        for (int w = 1; w < 4; ++w) {
            float v = wmin[w][t]; int x = widx[w][t];
            if (v < m) { m = v; ix = x; }
        }
        rowidx[t] = ix;
    }
    __syncthreads();

    float lsum = 0.f;
    const size_t base = (size_t)blk * 4096;
    float* oflat = out + base;
    #pragma unroll
    for (int j = 0; j < 16; ++j) {
        int f  = t + 256 * j;
        int nl = f >> 6, d = f & 63;
        int k  = rowidx[nl];
        float qv = E[(size_t)k * 64 + d];
        float zf = zs[d][nl];
        float df = qv - zf;
        lsum += df * df;
        oflat[f] = qv;
    }
    #pragma unroll
    for (int off = 32; off >= 1; off >>= 1) lsum += __shfl_down(lsum, off, 64);
    if (i == 0) wsum[wid] = lsum;
    __syncthreads();
    if (t == 0) {
        float s = (wsum[0] + wsum[1]) + (wsum[2] + wsum[3]);
        if (partial) partial[blk] = s;
        else         atomicAdd(&out[NDTOT + 1], s);
    }
}

__global__ __launch_bounds__(256) void vq_fin(const float* __restrict__ partial,
                                              float* __restrict__ out, int npart) {
    if (npart > 0) {
        __shared__ float ps[256];
        float s = 0.f;
        for (int qq = threadIdx.x; qq < npart; qq += 256) s += partial[qq];
        ps[threadIdx.x] = s;
        __syncthreads();
        for (int st = 128; st >= 1; st >>= 1) {
            if (threadIdx.x < st) ps[threadIdx.x] += ps[threadIdx.x + st];
            __syncthreads();
        }
        if (threadIdx.x == 0) {
            float mse = ps[0] / (float)NDTOT;
            out[NDTOT]     = 0.25f * mse;   // commitment_loss
            out[NDTOT + 1] = mse;           // codebook_loss
        }
    } else {
        if (threadIdx.x == 0) {
            float mse = out[NDTOT + 1] / (float)NDTOT;
            out[NDTOT]     = 0.25f * mse;
            out[NDTOT + 1] = mse;
        }
    }
}

extern "C" void kernel_launch(void* const* d_in, const int* in_sizes, int n_in,
                              void* d_out, int out_size, void* d_ws, size_t ws_size,
                              hipStream_t stream) {
    const float* z = (const float*)d_in[0];
    const float* E = (const float*)d_in[1];
    float* out = (float*)d_out;

    const size_t EBF_BYTES = (size_t)KCB * 64 * 2;        // 131072
    const size_t need = EBF_BYTES + 4096;                 // Ebf + he2b

    if (ws_size >= need) {
        unsigned* EbfU = (unsigned*)d_ws;
        short* Ebf  = (short*)d_ws;
        float* he2b = (float*)((char*)d_ws + EBF_BYTES);
        hipLaunchKernelGGL(vq_prep, dim3(16), dim3(256), 0, stream, E, EbfU, he2b, out);
        hipLaunchKernelGGL(vq_mfma, dim3(MBLK), dim3(256), 0, stream,
                           z, E, Ebf, he2b, out);
    } else {
        hipLaunchKernelGGL(vq_init, dim3(1), dim3(64), 0, stream, out);
        hipLaunchKernelGGL(vq_main_fp32, dim3(1024), dim3(256), 0, stream, z, E, out, nullptr);
        hipLaunchKernelGGL(vq_fin, dim3(1), dim3(256), 0, stream, nullptr, out, 0);
    }
}

// Round 23
// 30.435 us; speedup vs baseline: 3.0844x; 1.1183x over previous
//
#include <hip/hip_runtime.h>

// Problem constants (B=16, C=64, H=64, W=64, K=1024, D=64)
#define HWSZ   4096
#define CCH    64
#define KCB    1024
#define NROW   65536
#define NDTOT  4194304
#define MBLK   256             // main-path blocks (1 per CU)
#define BROWS  256             // rows per block (4 waves x 64 rows)

typedef __attribute__((ext_vector_type(8))) short short8;
typedef __attribute__((ext_vector_type(4))) float f32x4;

typedef const __attribute__((address_space(1))) unsigned gas_u32;
typedef __attribute__((address_space(3))) unsigned las_u32;

__device__ __forceinline__ unsigned short f2bf_rn(float x) {
    union { float f; unsigned u; } v; v.f = x;
    unsigned r = (v.u + 0x7fffu + ((v.u >> 16) & 1u)) >> 16;
    return (unsigned short)r;
}

// ---------- prep: 16 blocks, 4 threads/code: E -> swizzled bf16 + he2b ----------
__global__ __launch_bounds__(256) void vq_prep(const float* __restrict__ E,
                                               unsigned* __restrict__ Ebf,
                                               float* __restrict__ he2b) {
    const int t = threadIdx.x;
    const int gid  = blockIdx.x * 256 + t;
    const int code = gid >> 2;           // 0..1023
    const int part = gid & 3;
    const float4* ep = (const float4*)(E + (size_t)code * 64 + part * 16);
    const unsigned sw = ((unsigned)code & 7u) << 2;   // T2 swizzle on dword index
    float s = 0.f;
    #pragma unroll
    for (int q = 0; q < 4; ++q) {
        float4 a = ep[q];
        s += a.x * a.x + a.y * a.y + a.z * a.z + a.w * a.w;
        unsigned lo = (unsigned)f2bf_rn(a.x) | ((unsigned)f2bf_rn(a.y) << 16);
        unsigned hi = (unsigned)f2bf_rn(a.z) | ((unsigned)f2bf_rn(a.w) << 16);
        unsigned base = (unsigned)code * 32 + part * 8 + q * 2;
        Ebf[base ^ sw]       = lo;       // (base+1)^sw == (base^sw)+1 (sw bits >= 2)
        Ebf[(base + 1) ^ sw] = hi;
    }
    s += __shfl_xor(s, 1, 64);
    s += __shfl_xor(s, 2, 64);
    if (part == 0) he2b[code] = 1.0f + 0.5f * s;
}

// ---------- main: 256 blocks x 256 thr (1/CU); wave = 64 rows x all 1024 codes ----------
// Measured-best configuration (r19, 30.5us): whole 128KB swizzled codebook + he2
// staged via global_load_lds DMA (zero staging VGPRs), rt=4 A-frags from global
// with per-rt fences (caps hoisted-load VGPR peak), barrier-free LDS scan with
// packed score|idx min3, butterfly reduce, loss from winning scores, 1-block fin.
__global__ __launch_bounds__(256, 2) void vq_mfma(const float* __restrict__ z,
                                                  const float* __restrict__ E,
                                                  const short* __restrict__ Ebf,
                                                  const float* __restrict__ he2g,
                                                  float* __restrict__ out,
                                                  float* __restrict__ partial) {
    __shared__ short lbs[65536];       // 128 KB: full swizzled codebook image
    __shared__ float he2l[1024];       // 4 KB biases
    __shared__ float wsum[4];

    const int t   = threadIdx.x;       // 0..255
    const int blk = blockIdx.x;        // 0..255
    const int n0  = blk * BROWS;
    const int bb  = n0 >> 12;
    const int wid = t >> 6, lane = t & 63, col = lane & 15, g = lane >> 4;
    const int hwb = (n0 & 4095) + wid * 64;          // wave's 64-row hw base
    const float* zw = z + (size_t)bb * CCH * HWSZ + hwb;

    // ---- stage full codebook: 8192 x 16B slots, 32 per thread (DMA, zero VGPRs) ----
    #pragma unroll
    for (int q = 0; q < 32; ++q) {
        int slot = q * 256 + t;        // dest = wave-uniform base + lane*16  ✓
        __builtin_amdgcn_global_load_lds((gas_u32*)((const char*)Ebf + (size_t)slot * 16),
                                         (las_u32*)((char*)lbs + slot * 16), 16, 0, 0);
    }
    // ---- stage he2: 256 x 16B slots, 1 per thread ----
    __builtin_amdgcn_global_load_lds((gas_u32*)((const char*)he2g + (size_t)t * 16),
                                     (las_u32*)((char*)he2l + t * 16), 16, 0, 0);

    // ---- A-frags rt=4 (64 rows/wave) + z^2, from global (overlaps DMA);
    // per-rt fences cap the hoisted-load VGPR peak (r10/r12 spill lesson) ----
    float z2 = 0.f;
    short8 af[4][2];
    #pragma unroll
    for (int rt = 0; rt < 4; ++rt) {
        #pragma unroll
        for (int ch = 0; ch < 2; ++ch) {
            short8 a;
            #pragma unroll
            for (int j = 0; j < 8; ++j) {
                int c = ch * 32 + g * 8 + j;
                float v = zw[(size_t)c * HWSZ + rt * 16 + col];
                z2 = fmaf(v, v, z2);
                union { float f; unsigned u; } uu; uu.f = v;
                a[j] = (short)((uu.u >> 16) ^ 0x8000u);   // -z, bf16 truncation
            }
            af[rt][ch] = a;
        }
        asm volatile("" ::: "memory");
    }

    __syncthreads();   // compiler emits vmcnt(0) drain before s_barrier: DMAs landed

    float pk[4][4];
    #pragma unroll
    for (int rt = 0; rt < 4; ++rt)
        #pragma unroll
        for (int r = 0; r < 4; ++r) pk[rt][r] = 3.0e38f;

    // per-lane swizzled LDS read offsets (shorts); code&7 == col&7 within a tile
    const int swz = (col & 7) << 3;
    const int ro0 = col * 64 + ((g * 8) ^ swz);
    const int ro1 = col * 64 + ((32 + g * 8) ^ swz);

    // ---- barrier-free scan: 32 code-tile pairs; 4 ds_read_b128 -> 16 MFMA each ----
    #pragma unroll 2
    for (int cp = 0; cp < 32; ++cp) {
        const int ct0 = cp * 2, ct1 = ct0 + 1;
        const short* Lb0 = lbs + ct0 * 1024;
        const short* Lb1 = lbs + ct1 * 1024;
        short8 b00 = *(const short8*)(Lb0 + ro0);
        short8 b01 = *(const short8*)(Lb0 + ro1);
        short8 b10 = *(const short8*)(Lb1 + ro0);
        short8 b11 = *(const short8*)(Lb1 + ro1);
        const float h0 = he2l[ct0 * 16 + col];       // broadcast reads
        const float h1 = he2l[ct1 * 16 + col];
        const unsigned code0 = (unsigned)(ct0 * 16 + col);
        const unsigned code1 = code0 + 16;
        f32x4 hv0 = {h0, h0, h0, h0};
        f32x4 hv1 = {h1, h1, h1, h1};
        #pragma unroll
        for (int rt = 0; rt < 4; ++rt) {
            f32x4 a0 = __builtin_amdgcn_mfma_f32_16x16x32_bf16(af[rt][0], b00, hv0, 0, 0, 0);
            a0 = __builtin_amdgcn_mfma_f32_16x16x32_bf16(af[rt][1], b01, a0, 0, 0, 0);
            f32x4 a1 = __builtin_amdgcn_mfma_f32_16x16x32_bf16(af[rt][0], b10, hv1, 0, 0, 0);
            a1 = __builtin_amdgcn_mfma_f32_16x16x32_bf16(af[rt][1], b11, a1, 0, 0, 0);
            #pragma unroll
            for (int r = 0; r < 4; ++r) {
                union { float f; unsigned u; } m0, m1;
                m0.f = a0[r]; m0.u = (m0.u & 0xFFFFFC00u) | code0;   // v_and_or_b32
                m1.f = a1[r]; m1.u = (m1.u & 0xFFFFFC00u) | code1;
                pk[rt][r] = fminf(fminf(pk[rt][r], m0.f), m1.f);     // v_min3_f32
            }
        }
    }

    // ---- butterfly min over 16 code-columns ----
    #pragma unroll
    for (int rt = 0; rt < 4; ++rt) {
        #pragma unroll
        for (int r = 0; r < 4; ++r) {
            float d = pk[rt][r];
            #pragma unroll
            for (int mask = 1; mask < 16; mask <<= 1)
                d = fminf(d, __shfl_xor(d, mask, 64));
            pk[rt][r] = d;
        }
    }

    // ---- epilogue: output = E rows (== z + (q - z) to 1 ulp), loss from scores ----
    float lsum = z2;
    const int rowbase = n0 + wid * 64;
    #pragma unroll
    for (int rt = 0; rt < 4; ++rt) {
        #pragma unroll
        for (int r = 0; r < 4; ++r) {
            union { float f; unsigned u; } b; b.f = pk[rt][r];
            unsigned kk = b.u & 1023u;
            if (col == 0) {                              // count each row's score once
                union { unsigned u; float f; } sc; sc.u = b.u & 0xFFFFFC00u;
                lsum += 2.0f * (sc.f - 1.0f);            // ||e||^2 - 2 z.e
            }
            int row = rt * 16 + g * 4 + r;
            float4 qv = *(const float4*)(E + (size_t)kk * 64 + col * 4);
            *(float4*)(out + ((size_t)(rowbase + row)) * 64 + col * 4) = qv;
        }
    }

    #pragma unroll
    for (int off = 32; off >= 1; off >>= 1) lsum += __shfl_down(lsum, off, 64);
    if (lane == 0) wsum[wid] = lsum;
    __syncthreads();
    if (t == 0) partial[blk] = (wsum[0] + wsum[1]) + (wsum[2] + wsum[3]);
}

// ---------- fallback fp32 path (round-1, correctness-proven) ----------
__global__ __launch_bounds__(64) void vq_init(float* out) {
    if (threadIdx.x == 0) { out[NDTOT] = 0.0f; out[NDTOT + 1] = 0.0f; }
}

__global__ __launch_bounds__(256, 4) void vq_main_fp32(const float* __restrict__ z,
                                                       const float* __restrict__ E,
                                                       float* __restrict__ out,
                                                       float* __restrict__ partial) {
    __shared__ float zs[64][65];
    __shared__ float e2s[KCB];
    __shared__ float wmin[4][64];
    __shared__ int   widx[4][64];
    __shared__ int   rowidx[64];
    __shared__ float wsum[4];

    const int t   = threadIdx.x;
    const int blk = blockIdx.x;
    const int n0  = blk << 6;
    const int bb  = n0 >> 12;
    const int hw0 = n0 & 4095;
    const float* zb = z + (size_t)bb * CCH * HWSZ + hw0;

    #pragma unroll
    for (int j = 0; j < 16; ++j) {
        int f = t + 256 * j;
        int c = f >> 6, i = f & 63;
        zs[c][i] = zb[(size_t)c * HWSZ + i];
    }
    for (int qq = t; qq < KCB; qq += 256) {
        const float4* ep = (const float4*)(E + (size_t)qq * 64);
        float s0 = 0.f;
        #pragma unroll
        for (int c4 = 0; c4 < 16; ++c4) {
            float4 a = ep[c4];
            s0 += a.x * a.x + a.y * a.y + a.z * a.z + a.w * a.w;
        }
        e2s[qq] = s0;
    }
    __syncthreads();

    const int i   = t & 63;
    const int wid = t >> 6;
    float zr[64];
    #pragma unroll
    for (int c = 0; c < 64; ++c) zr[c] = zs[c][i];

    float best = 3.4e38f;
    int   bi = 0;
    const int k0 = wid << 8;
    const float* Ew = E + (size_t)k0 * 64;
    for (int kk = 0; kk < 256; ++kk) {
        const float4* ek = (const float4*)(Ew + (size_t)kk * 64);
        float d0 = 0.f, d1 = 0.f, d2 = 0.f, d3 = 0.f;
        #pragma unroll
        for (int c4 = 0; c4 < 16; ++c4) {
            float4 a = ek[c4];
            d0 = fmaf(a.x, zr[4 * c4 + 0], d0);
            d1 = fmaf(a.y, zr[4 * c4 + 1], d1);
            d2 = fmaf(a.z, zr[4 * c4 + 2], d2);
            d3 = fmaf(a.w, zr[4 * c4 + 3], d3);
        }
        float dot  = (d0 + d1) + (d2 + d3);
        float dist = fmaf(-2.0f, dot, e2s[k0 + kk]);
        if (dist < best) { best = dist; bi = k0 + kk; }
    }
    wmin[wid][i] = best; widx[wid][i] = bi;
    __syncthreads();
    if (t < 64) {
        float m = wmin[0][t]; int ix = widx[0][t];
        #pragma unroll
        for (int w = 1; w < 4; ++w) {
            float v = wmin[w][t]; int x = widx[w][t];
            if (v < m) { m = v; ix = x; }
        }
        rowidx[t] = ix;
    }
    __syncthreads();

    float lsum = 0.f;
    const size_t base = (size_t)blk * 4096;
    float* oflat = out + base;
    #pragma unroll
    for (int j = 0; j < 16; ++j) {
        int f  = t + 256 * j;
        int nl = f >> 6, d = f & 63;
        int k  = rowidx[nl];
        float qv = E[(size_t)k * 64 + d];
        float zf = zs[d][nl];
        float df = qv - zf;
        lsum += df * df;
        oflat[f] = qv;
    }
    #pragma unroll
    for (int off = 32; off >= 1; off >>= 1) lsum += __shfl_down(lsum, off, 64);
    if (i == 0) wsum[wid] = lsum;
    __syncthreads();
    if (t == 0) {
        float s = (wsum[0] + wsum[1]) + (wsum[2] + wsum[3]);
        if (partial) partial[blk] = s;
        else         atomicAdd(&out[NDTOT + 1], s);
    }
}

__global__ __launch_bounds__(256) void vq_fin(const float* __restrict__ partial,
                                              float* __restrict__ out, int npart) {
    if (npart > 0) {
        __shared__ float ps[256];
        float s = 0.f;
        for (int qq = threadIdx.x; qq < npart; qq += 256) s += partial[qq];
        ps[threadIdx.x] = s;
        __syncthreads();
        for (int st = 128; st >= 1; st >>= 1) {
            if (threadIdx.x < st) ps[threadIdx.x] += ps[threadIdx.x + st];
            __syncthreads();
        }
        if (threadIdx.x == 0) {
            float mse = ps[0] / (float)NDTOT;
            out[NDTOT]     = 0.25f * mse;   // commitment_loss
            out[NDTOT + 1] = mse;           // codebook_loss
        }
    } else {
        if (threadIdx.x == 0) {
            float mse = out[NDTOT + 1] / (float)NDTOT;
            out[NDTOT]     = 0.25f * mse;
            out[NDTOT + 1] = mse;
        }
    }
}

extern "C" void kernel_launch(void* const* d_in, const int* in_sizes, int n_in,
                              void* d_out, int out_size, void* d_ws, size_t ws_size,
                              hipStream_t stream) {
    const float* z = (const float*)d_in[0];
    const float* E = (const float*)d_in[1];
    float* out = (float*)d_out;

    const size_t EBF_BYTES = (size_t)KCB * 64 * 2;                 // 131072
    const size_t need = EBF_BYTES + 4096 + MBLK * sizeof(float);   // Ebf + he2b + partial

    if (ws_size >= need) {
        unsigned* EbfU = (unsigned*)d_ws;
        short* Ebf  = (short*)d_ws;
        float* he2b = (float*)((char*)d_ws + EBF_BYTES);
        float* partial = (float*)((char*)d_ws + EBF_BYTES + 4096);
        hipLaunchKernelGGL(vq_prep, dim3(16), dim3(256), 0, stream, E, EbfU, he2b);
        hipLaunchKernelGGL(vq_mfma, dim3(MBLK), dim3(256), 0, stream,
                           z, E, Ebf, he2b, out, partial);
        hipLaunchKernelGGL(vq_fin, dim3(1), dim3(256), 0, stream, partial, out, MBLK);
    } else {
        hipLaunchKernelGGL(vq_init, dim3(1), dim3(64), 0, stream, out);
        hipLaunchKernelGGL(vq_main_fp32, dim3(1024), dim3(256), 0, stream, z, E, out, nullptr);
        hipLaunchKernelGGL(vq_fin, dim3(1), dim3(256), 0, stream, nullptr, out, 0);
    }
}